// Round 2
// baseline (1117.449 us; speedup 1.0000x reference)
//
#include <hip/hip_runtime.h>
#include <hip/hip_bf16.h>
#include <math.h>

typedef short short8 __attribute__((ext_vector_type(8)));
typedef float f32x4 __attribute__((ext_vector_type(4)));
typedef __hip_bfloat16 bf16;

// problem constants
#define KN 10
#define KC 512
#define KHW 1600
#define KH 40
#define KOC 128
#define KPW 42   // padded spatial (40+2)

// async global->LDS, 16B per lane; LDS dest must be wave-uniform base + lane*16
__device__ __forceinline__ void gl16(const void* g, void* l) {
  __builtin_amdgcn_global_load_lds(
      (const __attribute__((address_space(1))) unsigned int*)g,
      (__attribute__((address_space(3))) unsigned int*)l, 16, 0, 0);
}

// ---------------- block reduction helpers (fp64) ----------------
__device__ __forceinline__ double blockReduceSumD(double v) {
  __shared__ double tmpS[8];
  int lane = threadIdx.x & 63, wv = threadIdx.x >> 6;
  #pragma unroll
  for (int o = 32; o > 0; o >>= 1) v += __shfl_down(v, o);
  if (lane == 0) tmpS[wv] = v;
  __syncthreads();
  if (threadIdx.x == 0) {
    int nw = (blockDim.x + 63) >> 6;
    double s = 0;
    for (int i = 0; i < nw; i++) s += tmpS[i];
    tmpS[0] = s;
  }
  __syncthreads();
  double r = tmpS[0];
  __syncthreads();
  return r;
}

__device__ __forceinline__ double blockReduceMinD(double v) {
  __shared__ double tmpMn[8];
  int lane = threadIdx.x & 63, wv = threadIdx.x >> 6;
  #pragma unroll
  for (int o = 32; o > 0; o >>= 1) v = fmin(v, __shfl_down(v, o));
  if (lane == 0) tmpMn[wv] = v;
  __syncthreads();
  if (threadIdx.x == 0) {
    int nw = (blockDim.x + 63) >> 6;
    double s = tmpMn[0];
    for (int i = 1; i < nw; i++) s = fmin(s, tmpMn[i]);
    tmpMn[0] = s;
  }
  __syncthreads();
  double r = tmpMn[0];
  __syncthreads();
  return r;
}

__device__ __forceinline__ double blockReduceMaxD(double v) {
  __shared__ double tmpMx[8];
  int lane = threadIdx.x & 63, wv = threadIdx.x >> 6;
  #pragma unroll
  for (int o = 32; o > 0; o >>= 1) v = fmax(v, __shfl_down(v, o));
  if (lane == 0) tmpMx[wv] = v;
  __syncthreads();
  if (threadIdx.x == 0) {
    int nw = (blockDim.x + 63) >> 6;
    double s = tmpMx[0];
    for (int i = 1; i < nw; i++) s = fmax(s, tmpMx[i]);
    tmpMx[0] = s;
  }
  __syncthreads();
  double r = tmpMx[0];
  __syncthreads();
  return r;
}

// ---------------- small chain (fp64 for argsort stability) ----------------

__global__ void k_rnorm(const float* __restrict__ feats, double* __restrict__ rnorm) {
  int t = blockIdx.x * 256 + threadIdx.x;
  if (t >= KN * KHW) return;
  int n = t / KHW, k = t % KHW;
  const float* p = feats + (size_t)n * KC * KHW + k;
  double s = 0.0;
  for (int c = 0; c < KC; ++c) { double v = p[(size_t)c * KHW]; s += v * v; }
  double nn = sqrt(s);
  if (nn < 1e-12) nn = 1e-12;
  rnorm[t] = 1.0 / nn;
}

// NFT[n,k,c] = bf16(feats[n,c,k] * rnorm[n,k])
__global__ void k_nft(const float* __restrict__ feats, const double* __restrict__ rnorm,
                      bf16* __restrict__ NFT) {
  __shared__ float T[32][33];
  int n = blockIdx.z, k0 = blockIdx.x * 32, c0 = blockIdx.y * 32;
  int tx = threadIdx.x, ty = threadIdx.y;
  const float* fb = feats + ((size_t)n * KC + c0) * KHW + k0;
  #pragma unroll
  for (int ii = 0; ii < 4; ii++) {
    int cl = ty * 4 + ii;
    T[cl][tx] = fb[(size_t)cl * KHW + tx];
  }
  __syncthreads();
  bf16* ob = NFT + ((size_t)n * KHW + k0) * KC + c0;
  #pragma unroll
  for (int ii = 0; ii < 4; ii++) {
    int kl = ty * 4 + ii;
    float r = (float)rnorm[n * KHW + k0 + kl];
    ob[(size_t)kl * KC + tx] = __float2bfloat16(T[tx][kl] * r);
  }
}

__global__ void k_sivpre(const float* __restrict__ feats, const float* __restrict__ sism,
                         const double* __restrict__ rnorm, double* __restrict__ vbuf) {
  int b = blockIdx.x;
  int n = b / KC, c = b % KC;
  const float* f = feats + ((size_t)n * KC + c) * KHW;
  const float* s = sism + (size_t)n * KHW;
  const double* r = rnorm + (size_t)n * KHW;
  double acc = 0;
  for (int k = threadIdx.x; k < KHW; k += 256) acc += (double)f[k] * r[k] * (double)s[k];
  acc = blockReduceSumD(acc);
  if (threadIdx.x == 0) vbuf[b] = acc / (double)KHW;
}

__global__ void k_sivnorm(const double* __restrict__ vbuf, double* __restrict__ SIV) {
  int n = blockIdx.x;
  double v = vbuf[n * KC + threadIdx.x];
  double s2 = blockReduceSumD(v * v);
  double nn = sqrt(s2);
  if (nn < 1e-12) nn = 1e-12;
  SIV[n * KC + threadIdx.x] = v / nn;
}

__global__ void k_cm(const float* __restrict__ feats, const double* __restrict__ rnorm,
                     const double* __restrict__ SIV, double* __restrict__ cm) {
  __shared__ double sv[KN * KC];
  for (int i = threadIdx.x; i < KN * KC; i += 256) sv[i] = SIV[i];
  __syncthreads();
  int t = blockIdx.x * 256 + threadIdx.x;
  if (t >= KN * KHW) return;
  int n = t / KHW, k = t % KHW;
  const float* f = feats + (size_t)n * KC * KHW + k;
  double acc[KN];
  #pragma unroll
  for (int m = 0; m < KN; m++) acc[m] = 0.0;
  for (int c = 0; c < KC; ++c) {
    double fv = f[(size_t)c * KHW];
    #pragma unroll
    for (int m = 0; m < KN; m++) acc[m] += fv * sv[m * KC + c];
  }
  double r = rnorm[t];
  #pragma unroll
  for (int m = 0; m < KN; m++) cm[((size_t)n * KN + m) * KHW + k] = acc[m] * r;
}

__global__ void k_cmnorm(double* __restrict__ cm) {
  double* row = cm + (size_t)blockIdx.x * KHW;
  double s = 0;
  for (int k = threadIdx.x; k < KHW; k += 256) { double v = row[k]; s += v * v; }
  s = blockReduceSumD(s);
  double nn = sqrt(s);
  if (nn < 1e-12) nn = 1e-12;
  double rn = 1.0 / nn;
  for (int k = threadIdx.x; k < KHW; k += 256) row[k] *= rn;
}

__global__ void k_s(const double* __restrict__ cm, double* __restrict__ S) {
  int t = blockIdx.x * 256 + threadIdx.x;
  if (t >= KN * KHW) return;
  int n = t / KHW, k = t % KHW;
  double s = 0;
  #pragma unroll
  for (int m = 0; m < KN; m++) s += cm[((size_t)n * KN + m) * KHW + k];
  S[t] = s;
}

__global__ void k_t(const double* __restrict__ cm, const double* __restrict__ S,
                    double* __restrict__ tbuf) {
  int b = blockIdx.x;
  int n = b / KN;
  const double* row = cm + (size_t)b * KHW;
  const double* Sv = S + (size_t)n * KHW;
  double acc = 0;
  for (int k = threadIdx.x; k < KHW; k += 256) acc += row[k] * Sv[k];
  acc = blockReduceSumD(acc);
  if (threadIdx.x == 0) tbuf[b] = acc;
}

__global__ void k_wv(const double* __restrict__ tbuf, double* __restrict__ wv) {
  int n = threadIdx.x;
  if (n >= KN) return;
  double v[KN], mx = -1e300;
  #pragma unroll
  for (int m = 0; m < KN; m++) { v[m] = tbuf[n * KN + m]; mx = fmax(mx, v[m]); }
  double s = 0;
  #pragma unroll
  for (int m = 0; m < KN; m++) { v[m] = exp(v[m] - mx); s += v[m]; }
  #pragma unroll
  for (int m = 0; m < KN; m++) wv[n * KN + m] = v[m] / s;
}

__global__ void k_csa(const double* __restrict__ cm, const double* __restrict__ wv,
                      double* __restrict__ CSAd, float* __restrict__ CSAf) {
  __shared__ double w[KN];
  int n = blockIdx.x, tid = threadIdx.x;
  if (tid < KN) w[tid] = wv[n * KN + tid];
  __syncthreads();
  double v[7];
  int cnt = 0;
  double lmin = 1e300, lmax = -1e300;
  for (int k = tid; k < KHW; k += 256) {
    double a = 0;
    #pragma unroll
    for (int m = 0; m < KN; m++) a += cm[((size_t)n * KN + m) * KHW + k] * w[m];
    v[cnt++] = a;
    lmin = fmin(lmin, a);
    lmax = fmax(lmax, a);
  }
  double mn = blockReduceMinD(lmin);
  double mx = blockReduceMaxD(lmax);
  double inv = 1.0 / (mx - mn + 1e-12);
  cnt = 0;
  for (int k = tid; k < KHW; k += 256) {
    double nv = (v[cnt++] - mn) * inv;
    CSAd[(size_t)n * KHW + k] = nv;
    CSAf[(size_t)n * KHW + k] = (float)nv;
  }
}

// per-n descending argsort of CSA; emits INVERSE permutation (inv[idx[i]] = i)
__global__ void k_sort(const double* __restrict__ CSAd, int* __restrict__ inv) {
  __shared__ double key[2048];
  __shared__ int ki[2048];
  int n = blockIdx.x, tid = threadIdx.x;
  for (int i = tid; i < 2048; i += 256) {
    if (i < KHW) { key[i] = CSAd[(size_t)n * KHW + i]; ki[i] = i; }
    else { key[i] = -1e300; ki[i] = i; }
  }
  __syncthreads();
  for (int k = 2; k <= 2048; k <<= 1) {
    for (int j = k >> 1; j > 0; j >>= 1) {
      for (int t = tid; t < 1024; t += 256) {
        int i = ((t & ~(j - 1)) << 1) | (t & (j - 1));
        int p = i | j;
        double a = key[i], b = key[p];
        int ia = ki[i], ib = ki[p];
        bool desc = (i & k) == 0;
        bool sw = desc ? (a < b || (a == b && ia > ib))
                       : (a > b || (a == b && ia < ib));
        if (sw) { key[i] = b; key[p] = a; ki[i] = ib; ki[p] = ia; }
      }
      __syncthreads();
    }
  }
  for (int i = tid; i < KHW; i += 256) inv[n * KHW + ki[i]] = i;
}

// ---------------- weight prep (bf16, permuted by inv so Gram needs no gather) ----------------
// w1p[o][s][j] = w1[o][inv[j]][s]   (per-n inverse permutation; w1p has a per-n copy)
__global__ void k_prepw1(const float* __restrict__ w1, const int* __restrict__ inv,
                         bf16* __restrict__ w1p) {
  int t = blockIdx.x * 256 + threadIdx.x;
  if (t >= KOC * 9 * KHW) return;
  int n = blockIdx.y;
  int o = t / (9 * KHW), r = t % (9 * KHW);
  int s = r / KHW, j = r % KHW;
  int i = inv[n * KHW + j];
  w1p[(size_t)n * KOC * 9 * KHW + t] = __float2bfloat16(w1[((size_t)o * KHW + i) * 9 + s]);
}

__global__ void k_prepw2(const float* __restrict__ w2, bf16* __restrict__ w2p) {
  int t = blockIdx.x * 256 + threadIdx.x;
  if (t >= KOC * 9 * KOC) return;
  int o = t / (9 * KOC), r = t % (9 * KOC);
  int s = r / KOC, i = r % KOC;
  w2p[t] = __float2bfloat16(w2[(size_t)o * 9 * KOC + (size_t)i * 9 + s]);
}

// wsb[n][o][j] = ws[o][inv[j]]
__global__ void k_prepws(const float* __restrict__ ws, const int* __restrict__ inv,
                         bf16* __restrict__ wsb) {
  int t = blockIdx.x * 256 + threadIdx.x;
  if (t >= KOC * KHW) return;
  int n = blockIdx.y;
  int o = t / KHW, j = t % KHW;
  wsb[(size_t)n * KOC * KHW + t] = __float2bfloat16(ws[(size_t)o * KHW + inv[n * KHW + j]]);
}

// ---------------- Gram GEMM fused with CSA-scale + transpose + pad ----------------
// xpadT[n, y(p)+1, x(p)+1, j] = (sum_c NFT[n,p,c]*NFT[n,j,c]) * CSA[n,p]
__global__ __launch_bounds__(256) void k_gramx(const short* __restrict__ NFT,
                                               const float* __restrict__ CSAf,
                                               bf16* __restrict__ xpadT) {
  __shared__ short As[128 * 32];
  __shared__ short Bs[128 * 32];
  int n = blockIdx.z;
  int i0 = blockIdx.x * 128, j0 = blockIdx.y * 128;
  int tid = threadIdx.x, lane = tid & 63, wave = tid >> 6;
  int quad = lane >> 4, l15 = lane & 15;
  int wm = (wave >> 1) * 64, wn = (wave & 1) * 64;
  int ar = tid >> 2, ko = (tid & 3) * 8;
  int wb = (tid >> 6) * 512;  // wave-uniform LDS base (shorts)
  const short* base = NFT + (size_t)n * KHW * KC;
  int a0r = min(i0 + ar, KHW - 1), a1r = min(i0 + ar + 64, KHW - 1);
  int b0r = min(j0 + ar, KHW - 1), b1r = min(j0 + ar + 64, KHW - 1);
  const short* pa0 = base + (size_t)a0r * KC + ko;
  const short* pa1 = base + (size_t)a1r * KC + ko;
  const short* pb0 = base + (size_t)b0r * KC + ko;
  const short* pb1 = base + (size_t)b1r * KC + ko;
  f32x4 acc[4][4] = {};
  for (int k0 = 0; k0 < KC; k0 += 32) {
    __syncthreads();
    gl16(pa0 + k0, &As[wb]);
    gl16(pa1 + k0, &As[wb + 2048]);
    gl16(pb0 + k0, &Bs[wb]);
    gl16(pb1 + k0, &Bs[wb + 2048]);
    __syncthreads();
    short8 a[4], b[4];
    #pragma unroll
    for (int t = 0; t < 4; t++) a[t] = *(const short8*)&As[(wm + t * 16 + l15) * 32 + quad * 8];
    #pragma unroll
    for (int t = 0; t < 4; t++) b[t] = *(const short8*)&Bs[(wn + t * 16 + l15) * 32 + quad * 8];
    #pragma unroll
    for (int ti = 0; ti < 4; ti++)
      #pragma unroll
      for (int tj = 0; tj < 4; tj++)
        acc[ti][tj] = __builtin_amdgcn_mfma_f32_16x16x32_bf16(a[ti], b[tj], acc[ti][tj], 0, 0, 0);
  }
  bf16* xp = xpadT + (size_t)n * KPW * KPW * KHW;
  const float* cs = CSAf + n * KHW;
  for (int ti = 0; ti < 4; ti++) {
    int gr = i0 + wm + ti * 16 + quad * 4;
    for (int tj = 0; tj < 4; tj++) {
      int gc = j0 + wn + tj * 16 + l15;
      if (gc < KHW) {
        #pragma unroll
        for (int r = 0; r < 4; r++) {
          int p = gr + r;
          if (p < KHW) {
            int y = p / KH, x = p % KH;
            xp[((size_t)(y + 1) * KPW + (x + 1)) * KHW + gc] =
                __float2bfloat16(acc[ti][tj][r] * cs[p]);
          }
        }
      }
    }
  }
}

// ---------------- conv1 (3x3, 1600->128): 128x64 tile, K split over dy ----------------
__global__ __launch_bounds__(256) void k_conv1(const short* __restrict__ w1p,
                                               const short* __restrict__ xpadT,
                                               float* __restrict__ hbuf) {
  __shared__ short As[128 * 32];
  __shared__ short Bs[64 * 32];
  int p0 = blockIdx.x * 64, dy = blockIdx.y, n = blockIdx.z;
  int tid = threadIdx.x, lane = tid & 63, wave = tid >> 6;
  int quad = lane >> 4, l15 = lane & 15;
  int wm = (wave & 1) * 64, wn = (wave >> 1) * 32;
  int ar = tid >> 2, ko = (tid & 3) * 8;
  int wb = (tid >> 6) * 512;
  const short* xb = xpadT + (size_t)n * KPW * KPW * KHW;
  const short* wp = w1p + (size_t)n * KOC * 9 * KHW;
  int p = p0 + ar;           // ar in [0,64): B row
  int y0 = p / KH, x0 = p % KH;
  f32x4 acc[4][2] = {};
  for (int dx = 0; dx < 3; ++dx) {
    const short* a0 = wp + ((size_t)ar * 9 + dy * 3 + dx) * KHW + ko;
    const short* a1 = wp + ((size_t)(ar + 64) * 9 + dy * 3 + dx) * KHW + ko;
    const short* b0 = xb + ((size_t)(y0 + dy) * KPW + (x0 + dx)) * KHW + ko;
    for (int k0 = 0; k0 < KHW; k0 += 32) {
      __syncthreads();
      gl16(a0 + k0, &As[wb]);
      gl16(a1 + k0, &As[wb + 2048]);
      gl16(b0 + k0, &Bs[wb]);
      __syncthreads();
      short8 a[4], b[2];
      #pragma unroll
      for (int t = 0; t < 4; t++) a[t] = *(const short8*)&As[(wm + t * 16 + l15) * 32 + quad * 8];
      #pragma unroll
      for (int t = 0; t < 2; t++) b[t] = *(const short8*)&Bs[(wn + t * 16 + l15) * 32 + quad * 8];
      #pragma unroll
      for (int ti = 0; ti < 4; ti++)
        #pragma unroll
        for (int tj = 0; tj < 2; tj++)
          acc[ti][tj] = __builtin_amdgcn_mfma_f32_16x16x32_bf16(a[ti], b[tj], acc[ti][tj], 0, 0, 0);
    }
  }
  float* hb = hbuf + (size_t)n * KOC * KHW;
  for (int ti = 0; ti < 4; ti++) {
    int go = wm + ti * 16 + quad * 4;
    for (int tj = 0; tj < 2; tj++) {
      int gp = p0 + wn + tj * 16 + l15;
      #pragma unroll
      for (int r = 0; r < 4; r++)
        atomicAdd(&hb[(size_t)(go + r) * KHW + gp], acc[ti][tj][r]);
    }
  }
}

// ---------------- shortcut (1x1, 1600->128): 128x64 tile, K split in halves ----------------
__global__ __launch_bounds__(256) void k_scg(const short* __restrict__ wsb,
                                             const short* __restrict__ xpadT,
                                             float* __restrict__ scbuf) {
  __shared__ short As[128 * 32];
  __shared__ short Bs[64 * 32];
  int p0 = blockIdx.x * 64, kh = blockIdx.y, n = blockIdx.z;
  int tid = threadIdx.x, lane = tid & 63, wave = tid >> 6;
  int quad = lane >> 4, l15 = lane & 15;
  int wm = (wave & 1) * 64, wn = (wave >> 1) * 32;
  int ar = tid >> 2, ko = (tid & 3) * 8;
  int wb = (tid >> 6) * 512;
  const short* xb = xpadT + (size_t)n * KPW * KPW * KHW;
  const short* wp = wsb + (size_t)n * KOC * KHW;
  int p = p0 + ar;
  int y0 = p / KH, x0 = p % KH;
  const short* a0 = wp + (size_t)ar * KHW + ko;
  const short* a1 = wp + (size_t)(ar + 64) * KHW + ko;
  const short* b0 = xb + ((size_t)(y0 + 1) * KPW + (x0 + 1)) * KHW + ko;
  f32x4 acc[4][2] = {};
  for (int c = 0; c < 25; ++c) {
    int k0 = kh * 800 + c * 32;
    __syncthreads();
    gl16(a0 + k0, &As[wb]);
    gl16(a1 + k0, &As[wb + 2048]);
    gl16(b0 + k0, &Bs[wb]);
    __syncthreads();
    short8 a[4], b[2];
    #pragma unroll
    for (int t = 0; t < 4; t++) a[t] = *(const short8*)&As[(wm + t * 16 + l15) * 32 + quad * 8];
    #pragma unroll
    for (int t = 0; t < 2; t++) b[t] = *(const short8*)&Bs[(wn + t * 16 + l15) * 32 + quad * 8];
    #pragma unroll
    for (int ti = 0; ti < 4; ti++)
      #pragma unroll
      for (int tj = 0; tj < 2; tj++)
        acc[ti][tj] = __builtin_amdgcn_mfma_f32_16x16x32_bf16(a[ti], b[tj], acc[ti][tj], 0, 0, 0);
  }
  float* sb = scbuf + (size_t)n * KOC * KHW;
  for (int ti = 0; ti < 4; ti++) {
    int go = wm + ti * 16 + quad * 4;
    for (int tj = 0; tj < 2; tj++) {
      int gp = p0 + wn + tj * 16 + l15;
      #pragma unroll
      for (int r = 0; r < 4; r++)
        atomicAdd(&sb[(size_t)(go + r) * KHW + gp], acc[ti][tj][r]);
    }
  }
}

// h prep: hpadT[n, y+1, x+1, o] = bf16(relu(hbuf[n,o,p] + b1[o]))
__global__ void k_hprep(const float* __restrict__ hbuf, const float* __restrict__ b1,
                        bf16* __restrict__ hpadT) {
  __shared__ float T[32][132];
  int n = blockIdx.y, p0 = blockIdx.x * 32;
  int tx = threadIdx.x, ty = threadIdx.y;
  const float* hb = hbuf + (size_t)n * KOC * KHW;
  #pragma unroll
  for (int oc = 0; oc < 16; oc++) {
    int o = oc * 8 + ty;
    T[tx][o] = fmaxf(hb[(size_t)o * KHW + p0 + tx] + b1[o], 0.0f);
  }
  __syncthreads();
  bf16* hp = hpadT + (size_t)n * KPW * KPW * KOC;
  #pragma unroll
  for (int pc = 0; pc < 4; pc++) {
    int pl = ty * 4 + pc;
    int p = p0 + pl;
    int y = p / KH, x = p % KH;
    bf16* row = hp + ((size_t)(y + 1) * KPW + (x + 1)) * KOC;
    #pragma unroll
    for (int u = 0; u < 4; u++) row[tx * 4 + u] = __float2bfloat16(T[pl][tx * 4 + u]);
  }
}

// ---------------- conv2 (3x3, 128->128): 128x64 tile, K split over dy ----------------
__global__ __launch_bounds__(256) void k_conv2(const short* __restrict__ w2p,
                                               const short* __restrict__ hpadT,
                                               float* __restrict__ acc2) {
  __shared__ short As[128 * 32];
  __shared__ short Bs[64 * 32];
  int p0 = blockIdx.x * 64, dy = blockIdx.y, n = blockIdx.z;
  int tid = threadIdx.x, lane = tid & 63, wave = tid >> 6;
  int quad = lane >> 4, l15 = lane & 15;
  int wm = (wave & 1) * 64, wn = (wave >> 1) * 32;
  int ar = tid >> 2, ko = (tid & 3) * 8;
  int wb = (tid >> 6) * 512;
  const short* hb = hpadT + (size_t)n * KPW * KPW * KOC;
  int p = p0 + ar;
  int y0 = p / KH, x0 = p % KH;
  f32x4 acc[4][2] = {};
  for (int dx = 0; dx < 3; ++dx) {
    const short* a0 = w2p + (size_t)ar * 9 * KOC + (dy * 3 + dx) * KOC + ko;
    const short* a1 = w2p + (size_t)(ar + 64) * 9 * KOC + (dy * 3 + dx) * KOC + ko;
    const short* b0 = hb + ((size_t)(y0 + dy) * KPW + (x0 + dx)) * KOC + ko;
    for (int k0 = 0; k0 < KOC; k0 += 32) {
      __syncthreads();
      gl16(a0 + k0, &As[wb]);
      gl16(a1 + k0, &As[wb + 2048]);
      gl16(b0 + k0, &Bs[wb]);
      __syncthreads();
      short8 a[4], b[2];
      #pragma unroll
      for (int t = 0; t < 4; t++) a[t] = *(const short8*)&As[(wm + t * 16 + l15) * 32 + quad * 8];
      #pragma unroll
      for (int t = 0; t < 2; t++) b[t] = *(const short8*)&Bs[(wn + t * 16 + l15) * 32 + quad * 8];
      #pragma unroll
      for (int ti = 0; ti < 4; ti++)
        #pragma unroll
        for (int tj = 0; tj < 2; tj++)
          acc[ti][tj] = __builtin_amdgcn_mfma_f32_16x16x32_bf16(a[ti], b[tj], acc[ti][tj], 0, 0, 0);
    }
  }
  float* ab = acc2 + (size_t)n * KOC * KHW;
  for (int ti = 0; ti < 4; ti++) {
    int go = wm + ti * 16 + quad * 4;
    for (int tj = 0; tj < 2; tj++) {
      int gp = p0 + wn + tj * 16 + l15;
      #pragma unroll
      for (int r = 0; r < 4; r++)
        atomicAdd(&ab[(size_t)(go + r) * KHW + gp], acc[ti][tj][r]);
    }
  }
}

// out = relu(conv2 + b2 + shortcut + bs)
__global__ void k_final(const float* __restrict__ acc2, const float* __restrict__ scbuf,
                        const float* __restrict__ b2, const float* __restrict__ bs,
                        float* __restrict__ out) {
  int t = blockIdx.x * 256 + threadIdx.x;
  if (t >= KN * KOC * KHW) return;
  int o = (t / KHW) % KOC;
  out[t] = fmaxf(acc2[t] + scbuf[t] + b2[o] + bs[o], 0.0f);
}

// ---------------- launch ----------------
extern "C" void kernel_launch(void* const* d_in, const int* in_sizes, int n_in,
                              void* d_out, int out_size, void* d_ws, size_t ws_size,
                              hipStream_t stream) {
  const float* feats = (const float*)d_in[0];
  const float* sisms = (const float*)d_in[1];
  const float* w1 = (const float*)d_in[2];
  const float* b1 = (const float*)d_in[3];
  const float* w2 = (const float*)d_in[4];
  const float* b2 = (const float*)d_in[5];
  const float* wsc = (const float*)d_in[6];
  const float* bsc = (const float*)d_in[7];
  float* out = (float*)d_out;

  char* w = (char*)d_ws;
  auto carve = [&](size_t bytes) -> void* {
    void* p = (void*)w;
    w += (bytes + 255) & ~(size_t)255;
    return p;
  };
  bf16* NFT   = (bf16*)carve((size_t)KN * KHW * KC * 2);          // 16.4 MB
  bf16* xpadT = (bf16*)carve((size_t)KN * KPW * KPW * KHW * 2);   // 56.4 MB
  bf16* hpadT = (bf16*)carve((size_t)KN * KPW * KPW * KOC * 2);   // 4.5 MB
  float* hbuf  = (float*)carve((size_t)3 * KN * KOC * KHW * 4);   // 24.6 MB (h, sc, acc2)
  float* scbuf = hbuf + (size_t)KN * KOC * KHW;
  float* acc2  = scbuf + (size_t)KN * KOC * KHW;
  bf16* w1p   = (bf16*)carve((size_t)KN * KOC * 9 * KHW * 2);     // 36.9 MB (per-n permuted)
  bf16* w2p   = (bf16*)carve((size_t)KOC * 9 * KOC * 2);
  bf16* wsb   = (bf16*)carve((size_t)KN * KOC * KHW * 2);         // 4.1 MB
  double* rnorm = (double*)carve((size_t)KN * KHW * 8);
  double* vbuf  = (double*)carve((size_t)KN * KC * 8);
  double* SIV   = (double*)carve((size_t)KN * KC * 8);
  double* cm    = (double*)carve((size_t)KN * KN * KHW * 8);
  double* Sbuf  = (double*)carve((size_t)KN * KHW * 8);
  double* tbuf  = (double*)carve((size_t)KN * KN * 8);
  double* wvb   = (double*)carve((size_t)KN * KN * 8);
  double* CSAd  = (double*)carve((size_t)KN * KHW * 8);
  float* CSAf   = (float*)carve((size_t)KN * KHW * 4);
  int* invb     = (int*)carve((size_t)KN * KHW * 4);

  hipMemsetAsync(xpadT, 0, (size_t)KN * KPW * KPW * KHW * 2, stream);
  hipMemsetAsync(hpadT, 0, (size_t)KN * KPW * KPW * KOC * 2, stream);
  hipMemsetAsync(hbuf, 0, (size_t)3 * KN * KOC * KHW * 4, stream);

  k_rnorm<<<63, 256, 0, stream>>>(feats, rnorm);
  k_nft<<<dim3(50, 16, KN), dim3(32, 8), 0, stream>>>(feats, rnorm, NFT);
  k_sivpre<<<KN * KC, 256, 0, stream>>>(feats, sisms, rnorm, vbuf);
  k_sivnorm<<<KN, 512, 0, stream>>>(vbuf, SIV);
  k_cm<<<63, 256, 0, stream>>>(feats, rnorm, SIV, cm);
  k_cmnorm<<<KN * KN, 256, 0, stream>>>(cm);
  k_s<<<63, 256, 0, stream>>>(cm, Sbuf);
  k_t<<<KN * KN, 256, 0, stream>>>(cm, Sbuf, tbuf);
  k_wv<<<1, 64, 0, stream>>>(tbuf, wvb);
  k_csa<<<KN, 256, 0, stream>>>(cm, wvb, CSAd, CSAf);
  k_sort<<<KN, 256, 0, stream>>>(CSAd, invb);

  k_prepw1<<<dim3(7200, KN), 256, 0, stream>>>(w1, invb, w1p);
  k_prepw2<<<576, 256, 0, stream>>>(w2, w2p);
  k_prepws<<<dim3(800, KN), 256, 0, stream>>>(wsc, invb, wsb);

  k_gramx<<<dim3(13, 13, KN), 256, 0, stream>>>((const short*)NFT, CSAf, xpadT);

  k_conv1<<<dim3(25, 3, KN), 256, 0, stream>>>((const short*)w1p, (const short*)xpadT, hbuf);
  k_scg<<<dim3(25, 2, KN), 256, 0, stream>>>((const short*)wsb, (const short*)xpadT, scbuf);
  k_hprep<<<dim3(50, KN), dim3(32, 8), 0, stream>>>(hbuf, b1, hpadT);
  k_conv2<<<dim3(25, 3, KN), 256, 0, stream>>>((const short*)w2p, (const short*)hpadT, acc2);
  k_final<<<8000, 256, 0, stream>>>(acc2, scbuf, b2, bsc, out);
}

// Round 3
// 655.839 us; speedup vs baseline: 1.7038x; 1.7038x over previous
//
#include <hip/hip_runtime.h>
#include <hip/hip_bf16.h>
#include <math.h>

typedef short short8 __attribute__((ext_vector_type(8)));
typedef float f32x4 __attribute__((ext_vector_type(4)));
typedef __hip_bfloat16 bf16;

// problem constants
#define KN 10
#define KC 512
#define KHW 1600
#define KH 40
#define KOC 128
#define KPW 42   // padded spatial (40+2)

// ---------------- block reduction helpers (fp64) ----------------
__device__ __forceinline__ double blockReduceSumD(double v) {
  __shared__ double tmpS[8];
  int lane = threadIdx.x & 63, wv = threadIdx.x >> 6;
  #pragma unroll
  for (int o = 32; o > 0; o >>= 1) v += __shfl_down(v, o);
  if (lane == 0) tmpS[wv] = v;
  __syncthreads();
  if (threadIdx.x == 0) {
    int nw = (blockDim.x + 63) >> 6;
    double s = 0;
    for (int i = 0; i < nw; i++) s += tmpS[i];
    tmpS[0] = s;
  }
  __syncthreads();
  double r = tmpS[0];
  __syncthreads();
  return r;
}

__device__ __forceinline__ double blockReduceMinD(double v) {
  __shared__ double tmpMn[8];
  int lane = threadIdx.x & 63, wv = threadIdx.x >> 6;
  #pragma unroll
  for (int o = 32; o > 0; o >>= 1) v = fmin(v, __shfl_down(v, o));
  if (lane == 0) tmpMn[wv] = v;
  __syncthreads();
  if (threadIdx.x == 0) {
    int nw = (blockDim.x + 63) >> 6;
    double s = tmpMn[0];
    for (int i = 1; i < nw; i++) s = fmin(s, tmpMn[i]);
    tmpMn[0] = s;
  }
  __syncthreads();
  double r = tmpMn[0];
  __syncthreads();
  return r;
}

__device__ __forceinline__ double blockReduceMaxD(double v) {
  __shared__ double tmpMx[8];
  int lane = threadIdx.x & 63, wv = threadIdx.x >> 6;
  #pragma unroll
  for (int o = 32; o > 0; o >>= 1) v = fmax(v, __shfl_down(v, o));
  if (lane == 0) tmpMx[wv] = v;
  __syncthreads();
  if (threadIdx.x == 0) {
    int nw = (blockDim.x + 63) >> 6;
    double s = tmpMx[0];
    for (int i = 1; i < nw; i++) s = fmax(s, tmpMx[i]);
    tmpMx[0] = s;
  }
  __syncthreads();
  double r = tmpMx[0];
  __syncthreads();
  return r;
}

// ---------------- small chain (fp64 for argsort stability) ----------------

__global__ void k_rnorm(const float* __restrict__ feats, double* __restrict__ rnorm) {
  int t = blockIdx.x * 256 + threadIdx.x;
  if (t >= KN * KHW) return;
  int n = t / KHW, k = t % KHW;
  const float* p = feats + (size_t)n * KC * KHW + k;
  double s = 0.0;
  for (int c = 0; c < KC; ++c) { double v = p[(size_t)c * KHW]; s += v * v; }
  double nn = sqrt(s);
  if (nn < 1e-12) nn = 1e-12;
  rnorm[t] = 1.0 / nn;
}

// NFT[n,k,c] = bf16(feats[n,c,k] * rnorm[n,k])
__global__ void k_nft(const float* __restrict__ feats, const double* __restrict__ rnorm,
                      bf16* __restrict__ NFT) {
  __shared__ float T[32][33];
  int n = blockIdx.z, k0 = blockIdx.x * 32, c0 = blockIdx.y * 32;
  int tx = threadIdx.x, ty = threadIdx.y;
  const float* fb = feats + ((size_t)n * KC + c0) * KHW + k0;
  #pragma unroll
  for (int ii = 0; ii < 4; ii++) {
    int cl = ty * 4 + ii;
    T[cl][tx] = fb[(size_t)cl * KHW + tx];
  }
  __syncthreads();
  bf16* ob = NFT + ((size_t)n * KHW + k0) * KC + c0;
  #pragma unroll
  for (int ii = 0; ii < 4; ii++) {
    int kl = ty * 4 + ii;
    float r = (float)rnorm[n * KHW + k0 + kl];
    ob[(size_t)kl * KC + tx] = __float2bfloat16(T[tx][kl] * r);
  }
}

__global__ void k_sivpre(const float* __restrict__ feats, const float* __restrict__ sism,
                         const double* __restrict__ rnorm, double* __restrict__ vbuf) {
  int b = blockIdx.x;
  int n = b / KC, c = b % KC;
  const float* f = feats + ((size_t)n * KC + c) * KHW;
  const float* s = sism + (size_t)n * KHW;
  const double* r = rnorm + (size_t)n * KHW;
  double acc = 0;
  for (int k = threadIdx.x; k < KHW; k += 256) acc += (double)f[k] * r[k] * (double)s[k];
  acc = blockReduceSumD(acc);
  if (threadIdx.x == 0) vbuf[b] = acc / (double)KHW;
}

__global__ void k_sivnorm(const double* __restrict__ vbuf, double* __restrict__ SIV) {
  int n = blockIdx.x;
  double v = vbuf[n * KC + threadIdx.x];
  double s2 = blockReduceSumD(v * v);
  double nn = sqrt(s2);
  if (nn < 1e-12) nn = 1e-12;
  SIV[n * KC + threadIdx.x] = v / nn;
}

__global__ void k_cm(const float* __restrict__ feats, const double* __restrict__ rnorm,
                     const double* __restrict__ SIV, double* __restrict__ cm) {
  __shared__ double sv[KN * KC];
  for (int i = threadIdx.x; i < KN * KC; i += 256) sv[i] = SIV[i];
  __syncthreads();
  int t = blockIdx.x * 256 + threadIdx.x;
  if (t >= KN * KHW) return;
  int n = t / KHW, k = t % KHW;
  const float* f = feats + (size_t)n * KC * KHW + k;
  double acc[KN];
  #pragma unroll
  for (int m = 0; m < KN; m++) acc[m] = 0.0;
  for (int c = 0; c < KC; ++c) {
    double fv = f[(size_t)c * KHW];
    #pragma unroll
    for (int m = 0; m < KN; m++) acc[m] += fv * sv[m * KC + c];
  }
  double r = rnorm[t];
  #pragma unroll
  for (int m = 0; m < KN; m++) cm[((size_t)n * KN + m) * KHW + k] = acc[m] * r;
}

__global__ void k_cmnorm(double* __restrict__ cm) {
  double* row = cm + (size_t)blockIdx.x * KHW;
  double s = 0;
  for (int k = threadIdx.x; k < KHW; k += 256) { double v = row[k]; s += v * v; }
  s = blockReduceSumD(s);
  double nn = sqrt(s);
  if (nn < 1e-12) nn = 1e-12;
  double rn = 1.0 / nn;
  for (int k = threadIdx.x; k < KHW; k += 256) row[k] *= rn;
}

__global__ void k_s(const double* __restrict__ cm, double* __restrict__ S) {
  int t = blockIdx.x * 256 + threadIdx.x;
  if (t >= KN * KHW) return;
  int n = t / KHW, k = t % KHW;
  double s = 0;
  #pragma unroll
  for (int m = 0; m < KN; m++) s += cm[((size_t)n * KN + m) * KHW + k];
  S[t] = s;
}

__global__ void k_t(const double* __restrict__ cm, const double* __restrict__ S,
                    double* __restrict__ tbuf) {
  int b = blockIdx.x;
  int n = b / KN;
  const double* row = cm + (size_t)b * KHW;
  const double* Sv = S + (size_t)n * KHW;
  double acc = 0;
  for (int k = threadIdx.x; k < KHW; k += 256) acc += row[k] * Sv[k];
  acc = blockReduceSumD(acc);
  if (threadIdx.x == 0) tbuf[b] = acc;
}

__global__ void k_wv(const double* __restrict__ tbuf, double* __restrict__ wv) {
  int n = threadIdx.x;
  if (n >= KN) return;
  double v[KN], mx = -1e300;
  #pragma unroll
  for (int m = 0; m < KN; m++) { v[m] = tbuf[n * KN + m]; mx = fmax(mx, v[m]); }
  double s = 0;
  #pragma unroll
  for (int m = 0; m < KN; m++) { v[m] = exp(v[m] - mx); s += v[m]; }
  #pragma unroll
  for (int m = 0; m < KN; m++) wv[n * KN + m] = v[m] / s;
}

__global__ void k_csa(const double* __restrict__ cm, const double* __restrict__ wv,
                      double* __restrict__ CSAd, float* __restrict__ CSAf) {
  __shared__ double w[KN];
  int n = blockIdx.x, tid = threadIdx.x;
  if (tid < KN) w[tid] = wv[n * KN + tid];
  __syncthreads();
  double v[7];
  int cnt = 0;
  double lmin = 1e300, lmax = -1e300;
  for (int k = tid; k < KHW; k += 256) {
    double a = 0;
    #pragma unroll
    for (int m = 0; m < KN; m++) a += cm[((size_t)n * KN + m) * KHW + k] * w[m];
    v[cnt++] = a;
    lmin = fmin(lmin, a);
    lmax = fmax(lmax, a);
  }
  double mn = blockReduceMinD(lmin);
  double mx = blockReduceMaxD(lmax);
  double inv = 1.0 / (mx - mn + 1e-12);
  cnt = 0;
  for (int k = tid; k < KHW; k += 256) {
    double nv = (v[cnt++] - mn) * inv;
    CSAd[(size_t)n * KHW + k] = nv;
    CSAf[(size_t)n * KHW + k] = (float)nv;
  }
}

// per-n descending argsort of CSA; emits INVERSE permutation (inv[idx[i]] = i)
__global__ void k_sort(const double* __restrict__ CSAd, int* __restrict__ inv) {
  __shared__ double key[2048];
  __shared__ int ki[2048];
  int n = blockIdx.x, tid = threadIdx.x;
  for (int i = tid; i < 2048; i += 256) {
    if (i < KHW) { key[i] = CSAd[(size_t)n * KHW + i]; ki[i] = i; }
    else { key[i] = -1e300; ki[i] = i; }
  }
  __syncthreads();
  for (int k = 2; k <= 2048; k <<= 1) {
    for (int j = k >> 1; j > 0; j >>= 1) {
      for (int t = tid; t < 1024; t += 256) {
        int i = ((t & ~(j - 1)) << 1) | (t & (j - 1));
        int p = i | j;
        double a = key[i], b = key[p];
        int ia = ki[i], ib = ki[p];
        bool desc = (i & k) == 0;
        bool sw = desc ? (a < b || (a == b && ia > ib))
                       : (a > b || (a == b && ia < ib));
        if (sw) { key[i] = b; key[p] = a; ki[i] = ib; ki[p] = ia; }
      }
      __syncthreads();
    }
  }
  for (int i = tid; i < KHW; i += 256) inv[n * KHW + ki[i]] = i;
}

// ---------------- weight prep (bf16, permuted by inv so Gram needs no gather) ----------------
__global__ void k_prepw1(const float* __restrict__ w1, const int* __restrict__ inv,
                         bf16* __restrict__ w1p) {
  int t = blockIdx.x * 256 + threadIdx.x;
  if (t >= KOC * 9 * KHW) return;
  int n = blockIdx.y;
  int o = t / (9 * KHW), r = t % (9 * KHW);
  int s = r / KHW, j = r % KHW;
  int i = inv[n * KHW + j];
  w1p[(size_t)n * KOC * 9 * KHW + t] = __float2bfloat16(w1[((size_t)o * KHW + i) * 9 + s]);
}

__global__ void k_prepw2(const float* __restrict__ w2, bf16* __restrict__ w2p) {
  int t = blockIdx.x * 256 + threadIdx.x;
  if (t >= KOC * 9 * KOC) return;
  int o = t / (9 * KOC), r = t % (9 * KOC);
  int s = r / KOC, i = r % KOC;
  w2p[t] = __float2bfloat16(w2[(size_t)o * 9 * KOC + (size_t)i * 9 + s]);
}

__global__ void k_prepws(const float* __restrict__ ws, const int* __restrict__ inv,
                         bf16* __restrict__ wsb) {
  int t = blockIdx.x * 256 + threadIdx.x;
  if (t >= KOC * KHW) return;
  int n = blockIdx.y;
  int o = t / KHW, j = t % KHW;
  wsb[(size_t)n * KOC * KHW + t] = __float2bfloat16(ws[(size_t)o * KHW + inv[n * KHW + j]]);
}

// ---------------- Gram GEMM fused with CSA-scale + transpose + pad ----------------
// xpadT[n, y(p)+1, x(p)+1, j] = (sum_c NFT[n,p,c]*NFT[n,j,c]) * CSA[n,p]
// Epilogue stages the C-tile in LDS and writes 256B-contiguous row chunks.
__global__ __launch_bounds__(256) void k_gramx(const short* __restrict__ NFT,
                                               const float* __restrict__ CSAf,
                                               bf16* __restrict__ xpadT) {
  __shared__ short smem[128 * 136];          // 34.8 KB; aliased As/Bs/Cs
  short* As = smem;                          // [128][40]
  short* Bs = smem + 128 * 40;               // [128][40]
  short* Cs = smem;                          // [128][136] (reused after K-loop)
  int n = blockIdx.z;
  int i0 = blockIdx.x * 128, j0 = blockIdx.y * 128;
  int tid = threadIdx.x, lane = tid & 63, wave = tid >> 6;
  int quad = lane >> 4, l15 = lane & 15;
  int wm = (wave >> 1) * 64, wn = (wave & 1) * 64;
  int ar = tid >> 2, ko = (tid & 3) * 8;
  const short* base = NFT + (size_t)n * KHW * KC;
  int a0r = min(i0 + ar, KHW - 1), a1r = min(i0 + ar + 64, KHW - 1);
  int b0r = min(j0 + ar, KHW - 1), b1r = min(j0 + ar + 64, KHW - 1);
  const short* pa0 = base + (size_t)a0r * KC + ko;
  const short* pa1 = base + (size_t)a1r * KC + ko;
  const short* pb0 = base + (size_t)b0r * KC + ko;
  const short* pb1 = base + (size_t)b1r * KC + ko;
  f32x4 acc[4][4] = {};
  for (int k0 = 0; k0 < KC; k0 += 32) {
    __syncthreads();
    *(float4*)&As[ar * 40 + ko]        = *(const float4*)&pa0[k0];
    *(float4*)&As[(ar + 64) * 40 + ko] = *(const float4*)&pa1[k0];
    *(float4*)&Bs[ar * 40 + ko]        = *(const float4*)&pb0[k0];
    *(float4*)&Bs[(ar + 64) * 40 + ko] = *(const float4*)&pb1[k0];
    __syncthreads();
    short8 a[4], b[4];
    #pragma unroll
    for (int t = 0; t < 4; t++) a[t] = *(const short8*)&As[(wm + t * 16 + l15) * 40 + quad * 8];
    #pragma unroll
    for (int t = 0; t < 4; t++) b[t] = *(const short8*)&Bs[(wn + t * 16 + l15) * 40 + quad * 8];
    #pragma unroll
    for (int ti = 0; ti < 4; ti++)
      #pragma unroll
      for (int tj = 0; tj < 4; tj++)
        acc[ti][tj] = __builtin_amdgcn_mfma_f32_16x16x32_bf16(a[ti], b[tj], acc[ti][tj], 0, 0, 0);
  }
  const float* cs = CSAf + n * KHW;
  __syncthreads();   // all frag reads done; safe to overwrite smem as Cs
  #pragma unroll
  for (int ti = 0; ti < 4; ti++) {
    int lr = wm + ti * 16 + quad * 4;
    float csv[4];
    #pragma unroll
    for (int r = 0; r < 4; r++) csv[r] = cs[min(i0 + lr + r, KHW - 1)];
    #pragma unroll
    for (int tj = 0; tj < 4; tj++) {
      int lc = wn + tj * 16 + l15;
      #pragma unroll
      for (int r = 0; r < 4; r++)
        *(bf16*)&Cs[(lr + r) * 136 + lc] = __float2bfloat16(acc[ti][tj][r] * csv[r]);
    }
  }
  __syncthreads();
  bf16* xp = xpadT + (size_t)n * KPW * KPW * KHW;
  #pragma unroll
  for (int pass = 0; pass < 8; pass++) {
    int row = pass * 16 + (tid >> 4);
    int p = i0 + row;
    int j = j0 + (tid & 15) * 8;
    if (p < KHW && j < KHW) {
      int y = p / KH, x = p % KH;
      *(float4*)&xp[((size_t)(y + 1) * KPW + (x + 1)) * KHW + j] =
          *(const float4*)&Cs[row * 136 + (tid & 15) * 8];
    }
  }
}

// ---------------- conv1 (3x3, 1600->128): 128x64 tile, K split over dy ----------------
__global__ __launch_bounds__(256) void k_conv1(const short* __restrict__ w1p,
                                               const short* __restrict__ xpadT,
                                               float* __restrict__ hbuf) {
  __shared__ short As[128][40];
  __shared__ short Bs[64][40];
  int p0 = blockIdx.x * 64, dy = blockIdx.y, n = blockIdx.z;
  int tid = threadIdx.x, lane = tid & 63, wave = tid >> 6;
  int quad = lane >> 4, l15 = lane & 15;
  int wm = (wave & 1) * 64, wn = (wave >> 1) * 32;
  int ar = tid >> 2, ko = (tid & 3) * 8;
  const short* xb = xpadT + (size_t)n * KPW * KPW * KHW;
  const short* wp = w1p + (size_t)n * KOC * 9 * KHW;
  int p = p0 + ar;
  int y0 = p / KH, x0 = p % KH;
  f32x4 acc[4][2] = {};
  for (int dx = 0; dx < 3; ++dx) {
    const short* a0 = wp + ((size_t)ar * 9 + dy * 3 + dx) * KHW + ko;
    const short* a1 = wp + ((size_t)(ar + 64) * 9 + dy * 3 + dx) * KHW + ko;
    const short* b0 = xb + ((size_t)(y0 + dy) * KPW + (x0 + dx)) * KHW + ko;
    for (int k0 = 0; k0 < KHW; k0 += 32) {
      __syncthreads();
      *(float4*)&As[ar][ko]      = *(const float4*)&a0[k0];
      *(float4*)&As[ar + 64][ko] = *(const float4*)&a1[k0];
      *(float4*)&Bs[ar][ko]      = *(const float4*)&b0[k0];
      __syncthreads();
      short8 a[4], b[2];
      #pragma unroll
      for (int t = 0; t < 4; t++) a[t] = *(const short8*)&As[wm + t * 16 + l15][quad * 8];
      #pragma unroll
      for (int t = 0; t < 2; t++) b[t] = *(const short8*)&Bs[wn + t * 16 + l15][quad * 8];
      #pragma unroll
      for (int ti = 0; ti < 4; ti++)
        #pragma unroll
        for (int tj = 0; tj < 2; tj++)
          acc[ti][tj] = __builtin_amdgcn_mfma_f32_16x16x32_bf16(a[ti], b[tj], acc[ti][tj], 0, 0, 0);
    }
  }
  float* hb = hbuf + (size_t)n * KOC * KHW;
  for (int ti = 0; ti < 4; ti++) {
    int go = wm + ti * 16 + quad * 4;
    for (int tj = 0; tj < 2; tj++) {
      int gp = p0 + wn + tj * 16 + l15;
      #pragma unroll
      for (int r = 0; r < 4; r++)
        atomicAdd(&hb[(size_t)(go + r) * KHW + gp], acc[ti][tj][r]);
    }
  }
}

// ---------------- shortcut (1x1, 1600->128): 128x64 tile, K split in halves ----------------
__global__ __launch_bounds__(256) void k_scg(const short* __restrict__ wsb,
                                             const short* __restrict__ xpadT,
                                             float* __restrict__ scbuf) {
  __shared__ short As[128][40];
  __shared__ short Bs[64][40];
  int p0 = blockIdx.x * 64, kh = blockIdx.y, n = blockIdx.z;
  int tid = threadIdx.x, lane = tid & 63, wave = tid >> 6;
  int quad = lane >> 4, l15 = lane & 15;
  int wm = (wave & 1) * 64, wn = (wave >> 1) * 32;
  int ar = tid >> 2, ko = (tid & 3) * 8;
  const short* xb = xpadT + (size_t)n * KPW * KPW * KHW;
  const short* wp = wsb + (size_t)n * KOC * KHW;
  int p = p0 + ar;
  int y0 = p / KH, x0 = p % KH;
  const short* a0 = wp + (size_t)ar * KHW + ko;
  const short* a1 = wp + (size_t)(ar + 64) * KHW + ko;
  const short* b0 = xb + ((size_t)(y0 + 1) * KPW + (x0 + 1)) * KHW + ko;
  f32x4 acc[4][2] = {};
  for (int c = 0; c < 25; ++c) {
    int k0 = kh * 800 + c * 32;
    __syncthreads();
    *(float4*)&As[ar][ko]      = *(const float4*)&a0[k0];
    *(float4*)&As[ar + 64][ko] = *(const float4*)&a1[k0];
    *(float4*)&Bs[ar][ko]      = *(const float4*)&b0[k0];
    __syncthreads();
    short8 a[4], b[2];
    #pragma unroll
    for (int t = 0; t < 4; t++) a[t] = *(const short8*)&As[wm + t * 16 + l15][quad * 8];
    #pragma unroll
    for (int t = 0; t < 2; t++) b[t] = *(const short8*)&Bs[wn + t * 16 + l15][quad * 8];
    #pragma unroll
    for (int ti = 0; ti < 4; ti++)
      #pragma unroll
      for (int tj = 0; tj < 2; tj++)
        acc[ti][tj] = __builtin_amdgcn_mfma_f32_16x16x32_bf16(a[ti], b[tj], acc[ti][tj], 0, 0, 0);
  }
  float* sb = scbuf + (size_t)n * KOC * KHW;
  for (int ti = 0; ti < 4; ti++) {
    int go = wm + ti * 16 + quad * 4;
    for (int tj = 0; tj < 2; tj++) {
      int gp = p0 + wn + tj * 16 + l15;
      #pragma unroll
      for (int r = 0; r < 4; r++)
        atomicAdd(&sb[(size_t)(go + r) * KHW + gp], acc[ti][tj][r]);
    }
  }
}

// h prep: hpadT[n, y+1, x+1, o] = bf16(relu(hbuf[n,o,p] + b1[o]))
__global__ void k_hprep(const float* __restrict__ hbuf, const float* __restrict__ b1,
                        bf16* __restrict__ hpadT) {
  __shared__ float T[32][132];
  int n = blockIdx.y, p0 = blockIdx.x * 32;
  int tx = threadIdx.x, ty = threadIdx.y;
  const float* hb = hbuf + (size_t)n * KOC * KHW;
  #pragma unroll
  for (int oc = 0; oc < 16; oc++) {
    int o = oc * 8 + ty;
    T[tx][o] = fmaxf(hb[(size_t)o * KHW + p0 + tx] + b1[o], 0.0f);
  }
  __syncthreads();
  bf16* hp = hpadT + (size_t)n * KPW * KPW * KOC;
  #pragma unroll
  for (int pc = 0; pc < 4; pc++) {
    int pl = ty * 4 + pc;
    int p = p0 + pl;
    int y = p / KH, x = p % KH;
    bf16* row = hp + ((size_t)(y + 1) * KPW + (x + 1)) * KOC;
    #pragma unroll
    for (int u = 0; u < 4; u++) row[tx * 4 + u] = __float2bfloat16(T[pl][tx * 4 + u]);
  }
}

// ---------------- conv2 (3x3, 128->128): 128x64 tile, K split over dy ----------------
__global__ __launch_bounds__(256) void k_conv2(const short* __restrict__ w2p,
                                               const short* __restrict__ hpadT,
                                               float* __restrict__ acc2) {
  __shared__ short As[128][40];
  __shared__ short Bs[64][40];
  int p0 = blockIdx.x * 64, dy = blockIdx.y, n = blockIdx.z;
  int tid = threadIdx.x, lane = tid & 63, wave = tid >> 6;
  int quad = lane >> 4, l15 = lane & 15;
  int wm = (wave & 1) * 64, wn = (wave >> 1) * 32;
  int ar = tid >> 2, ko = (tid & 3) * 8;
  const short* hb = hpadT + (size_t)n * KPW * KPW * KOC;
  int p = p0 + ar;
  int y0 = p / KH, x0 = p % KH;
  f32x4 acc[4][2] = {};
  for (int dx = 0; dx < 3; ++dx) {
    const short* a0 = w2p + (size_t)ar * 9 * KOC + (dy * 3 + dx) * KOC + ko;
    const short* a1 = w2p + (size_t)(ar + 64) * 9 * KOC + (dy * 3 + dx) * KOC + ko;
    const short* b0 = hb + ((size_t)(y0 + dy) * KPW + (x0 + dx)) * KOC + ko;
    for (int k0 = 0; k0 < KOC; k0 += 32) {
      __syncthreads();
      *(float4*)&As[ar][ko]      = *(const float4*)&a0[k0];
      *(float4*)&As[ar + 64][ko] = *(const float4*)&a1[k0];
      *(float4*)&Bs[ar][ko]      = *(const float4*)&b0[k0];
      __syncthreads();
      short8 a[4], b[2];
      #pragma unroll
      for (int t = 0; t < 4; t++) a[t] = *(const short8*)&As[wm + t * 16 + l15][quad * 8];
      #pragma unroll
      for (int t = 0; t < 2; t++) b[t] = *(const short8*)&Bs[wn + t * 16 + l15][quad * 8];
      #pragma unroll
      for (int ti = 0; ti < 4; ti++)
        #pragma unroll
        for (int tj = 0; tj < 2; tj++)
          acc[ti][tj] = __builtin_amdgcn_mfma_f32_16x16x32_bf16(a[ti], b[tj], acc[ti][tj], 0, 0, 0);
    }
  }
  float* ab = acc2 + (size_t)n * KOC * KHW;
  for (int ti = 0; ti < 4; ti++) {
    int go = wm + ti * 16 + quad * 4;
    for (int tj = 0; tj < 2; tj++) {
      int gp = p0 + wn + tj * 16 + l15;
      #pragma unroll
      for (int r = 0; r < 4; r++)
        atomicAdd(&ab[(size_t)(go + r) * KHW + gp], acc[ti][tj][r]);
    }
  }
}

// out = relu(conv2 + b2 + shortcut + bs)
__global__ void k_final(const float* __restrict__ acc2, const float* __restrict__ scbuf,
                        const float* __restrict__ b2, const float* __restrict__ bs,
                        float* __restrict__ out) {
  int t = blockIdx.x * 256 + threadIdx.x;
  if (t >= KN * KOC * KHW) return;
  int o = (t / KHW) % KOC;
  out[t] = fmaxf(acc2[t] + scbuf[t] + b2[o] + bs[o], 0.0f);
}

// ---------------- launch ----------------
extern "C" void kernel_launch(void* const* d_in, const int* in_sizes, int n_in,
                              void* d_out, int out_size, void* d_ws, size_t ws_size,
                              hipStream_t stream) {
  const float* feats = (const float*)d_in[0];
  const float* sisms = (const float*)d_in[1];
  const float* w1 = (const float*)d_in[2];
  const float* b1 = (const float*)d_in[3];
  const float* w2 = (const float*)d_in[4];
  const float* b2 = (const float*)d_in[5];
  const float* wsc = (const float*)d_in[6];
  const float* bsc = (const float*)d_in[7];
  float* out = (float*)d_out;

  char* w = (char*)d_ws;
  auto carve = [&](size_t bytes) -> void* {
    void* p = (void*)w;
    w += (bytes + 255) & ~(size_t)255;
    return p;
  };
  bf16* NFT   = (bf16*)carve((size_t)KN * KHW * KC * 2);          // 16.4 MB
  bf16* xpadT = (bf16*)carve((size_t)KN * KPW * KPW * KHW * 2);   // 56.4 MB
  bf16* hpadT = (bf16*)carve((size_t)KN * KPW * KPW * KOC * 2);   // 4.5 MB
  float* hbuf  = (float*)carve((size_t)3 * KN * KOC * KHW * 4);   // 24.6 MB (h, sc, acc2)
  float* scbuf = hbuf + (size_t)KN * KOC * KHW;
  float* acc2  = scbuf + (size_t)KN * KOC * KHW;
  bf16* w1p   = (bf16*)carve((size_t)KN * KOC * 9 * KHW * 2);     // 36.9 MB (per-n permuted)
  bf16* w2p   = (bf16*)carve((size_t)KOC * 9 * KOC * 2);
  bf16* wsb   = (bf16*)carve((size_t)KN * KOC * KHW * 2);         // 4.1 MB
  double* rnorm = (double*)carve((size_t)KN * KHW * 8);
  double* vbuf  = (double*)carve((size_t)KN * KC * 8);
  double* SIV   = (double*)carve((size_t)KN * KC * 8);
  double* cm    = (double*)carve((size_t)KN * KN * KHW * 8);
  double* Sbuf  = (double*)carve((size_t)KN * KHW * 8);
  double* tbuf  = (double*)carve((size_t)KN * KN * 8);
  double* wvb   = (double*)carve((size_t)KN * KN * 8);
  double* CSAd  = (double*)carve((size_t)KN * KHW * 8);
  float* CSAf   = (float*)carve((size_t)KN * KHW * 4);
  int* invb     = (int*)carve((size_t)KN * KHW * 4);

  hipMemsetAsync(xpadT, 0, (size_t)KN * KPW * KPW * KHW * 2, stream);
  hipMemsetAsync(hpadT, 0, (size_t)KN * KPW * KPW * KOC * 2, stream);
  hipMemsetAsync(hbuf, 0, (size_t)3 * KN * KOC * KHW * 4, stream);

  k_rnorm<<<63, 256, 0, stream>>>(feats, rnorm);
  k_nft<<<dim3(50, 16, KN), dim3(32, 8), 0, stream>>>(feats, rnorm, NFT);
  k_sivpre<<<KN * KC, 256, 0, stream>>>(feats, sisms, rnorm, vbuf);
  k_sivnorm<<<KN, 512, 0, stream>>>(vbuf, SIV);
  k_cm<<<63, 256, 0, stream>>>(feats, rnorm, SIV, cm);
  k_cmnorm<<<KN * KN, 256, 0, stream>>>(cm);
  k_s<<<63, 256, 0, stream>>>(cm, Sbuf);
  k_t<<<KN * KN, 256, 0, stream>>>(cm, Sbuf, tbuf);
  k_wv<<<1, 64, 0, stream>>>(tbuf, wvb);
  k_csa<<<KN, 256, 0, stream>>>(cm, wvb, CSAd, CSAf);
  k_sort<<<KN, 256, 0, stream>>>(CSAd, invb);

  k_prepw1<<<dim3(7200, KN), 256, 0, stream>>>(w1, invb, w1p);
  k_prepw2<<<576, 256, 0, stream>>>(w2, w2p);
  k_prepws<<<dim3(800, KN), 256, 0, stream>>>(wsc, invb, wsb);

  k_gramx<<<dim3(13, 13, KN), 256, 0, stream>>>((const short*)NFT, CSAf, xpadT);

  k_conv1<<<dim3(25, 3, KN), 256, 0, stream>>>((const short*)w1p, (const short*)xpadT, hbuf);
  k_scg<<<dim3(25, 2, KN), 256, 0, stream>>>((const short*)wsb, (const short*)xpadT, scbuf);
  k_hprep<<<dim3(50, KN), dim3(32, 8), 0, stream>>>(hbuf, b1, hpadT);
  k_conv2<<<dim3(25, 3, KN), 256, 0, stream>>>((const short*)w2p, (const short*)hpadT, acc2);
  k_final<<<8000, 256, 0, stream>>>(acc2, scbuf, b2, bsc, out);
}